// Round 7
// baseline (430.730 us; speedup 1.0000x reference)
//
#include <hip/hip_runtime.h>

typedef __bf16 bf16x8 __attribute__((ext_vector_type(8)));
typedef float f32x4 __attribute__((ext_vector_type(4)));

// workspace layout (bf16 elements):
//   [0)      Weff   [112][128]  (unit, k)  pre-scaled by 2*log2e, col100 = 2*log2e*b_enc
//   [14336)  whh_p  [3][112][128]          r,z pre-scaled by log2e (col100 = log2e*(b_ih+b_hh));
//                                          n pre-scaled by 2*log2e (col100 = 2*log2e*b_hh_n)
//   [57344)  w1_p   [64][128]  (yunit, k)  col100 = b1
#define WS_WENC 0
#define WS_WHH  14336
#define WS_W1   57344
#define LOG2E 1.4426950408889634f

__device__ __forceinline__ float fast_exp2(float x) {
#if __has_builtin(__builtin_amdgcn_exp2f)
  return __builtin_amdgcn_exp2f(x);
#else
  return exp2f(x);
#endif
}
__device__ __forceinline__ float fast_rcp(float x) {
#if __has_builtin(__builtin_amdgcn_rcpf)
  return __builtin_amdgcn_rcpf(x);
#else
  return 1.f / x;
#endif
}

__global__ void prep_kernel(const float* __restrict__ w_enc,
                            const float* __restrict__ b_enc,
                            const float* __restrict__ w_hh,
                            const float* __restrict__ b_ih,
                            const float* __restrict__ b_hh,
                            const float* __restrict__ w1,
                            const float* __restrict__ b1,
                            __bf16* __restrict__ ws) {
  int idx = blockIdx.x * 256 + threadIdx.x;
  if (idx < 14336) {
    // Weff[i][n] = w_enc[i][n] + sum_k w_enc[i][100+k]*cos(2pi k n/100) - w_enc[i][151+k]*sin(2pi k n/100)
    int i = idx >> 7, n = idx & 127;
    float acc = 0.f;
    if (i < 100) {
      if (n < 100) {
        const float* wr = w_enc + i * 202;
        acc = wr[n];
        #pragma unroll 1
        for (int k = 0; k <= 50; ++k) {
          int m = (k * n) % 100;                 // exact range reduction
          float th = 0.062831853071795864f * (float)m;
          float s, c;
          __sincosf(th, &s, &c);
          acc += wr[100 + k] * c - wr[151 + k] * s;
        }
        acc *= 2.f * LOG2E;
      } else if (n == 100) {
        acc = 2.f * LOG2E * b_enc[i];
      }
    }
    ws[idx] = (__bf16)acc;
  } else if (idx < 57344) {
    int j = idx - 14336;
    int g = j / 14336;
    int rem = j - g * 14336;
    int u2 = rem >> 7, c2 = rem & 127;
    float scale = (g == 2) ? 2.f * LOG2E : LOG2E;
    float v = 0.f;
    if (u2 < 100) {
      if (c2 < 100) v = scale * w_hh[(g * 100 + u2) * 100 + c2];
      else if (c2 == 100) {
        v = (g == 2) ? scale * b_hh[200 + u2]
                     : scale * (b_ih[g * 100 + u2] + b_hh[g * 100 + u2]);
      }
    }
    ws[idx] = (__bf16)v;
  } else if (idx < 65536) {
    int j = idx - 57344;
    int r2 = j >> 7, c2 = j & 127;
    float v = 0.f;
    if (r2 < 50) {
      if (c2 < 100) v = w1[r2 * 100 + c2];
      else if (c2 == 100) v = b1[r2];
    }
    ws[idx] = (__bf16)v;
  }
}

__device__ __forceinline__ f32x4 mfma16(bf16x8 a, bf16x8 b, f32x4 c) {
  return __builtin_amdgcn_mfma_f32_16x16x32_bf16(a, b, c, 0, 0, 0);
}
// input already scaled by log2e:  sigm = rcp(1 + 2^-a)
__device__ __forceinline__ float sigm2(float a) { return fast_rcp(1.f + fast_exp2(-a)); }
// input already scaled by 2*log2e: tanh = 2*rcp(1 + 2^-b) - 1
__device__ __forceinline__ float tanh2(float b) { return fmaf(2.f, fast_rcp(1.f + fast_exp2(-b)), -1.f); }

// block = 448 threads = 7 waves, 32 sequences per block (two 16-seq MFMA groups
// sharing the per-wave resident w_hh fragments).
// wave w owns hidden units [16w, 16w+16) for BOTH groups.
// y-matmul transposed (w1 tile as A — RESIDENT IN VGPRS, 16 regs; h as B from LDS):
//   waves 0-2 -> g0 tiles 0-2; wave 3 -> tile 3 both groups; waves 4-6 -> g1 tiles 0-2.
// REGISTER DISCIPLINE (R5 lesson): h-fragments reloaded from LDS per use; only the
// small per-wave weight sets (wR 48 + wY 16 regs) are resident -> fits VGPR=64, no spill.
// LDS DISCIPLINE (R6 lesson): no wYl tile -> 24.5 KB total -> 4 blocks/CU resident
// (vs 1.7 at 42 KB), quadrupling the independent serial chains that hide step latency.
// Output staged in LDS, flushed coalesced after the loop: no in-loop global stores.
// MFMA 16x16x32_bf16; C/D layout: col = lane&15, row = 4*(lane>>4)+reg (HW-verified).
// Bias trick: h column 100 pinned to 1.0; weight column 100 carries the biases.
// All LDS tiles stride 136 elements (272 B) -> 2-way bank aliasing only (free).
__global__ __launch_bounds__(448, 4)
void gru_main(const float* __restrict__ enc,
              const float* __restrict__ w_ih,
              const float* __restrict__ b_ih,
              const float* __restrict__ w2,
              const float* __restrict__ b2,
              const __bf16* __restrict__ ws,
              float* __restrict__ out) {
  __shared__ __align__(16) __bf16 hbuf[2][32 * 136];  // [buf][seq 0..31][unit]
  __shared__ __align__(16) float xq[2][16][4];        // y tile-partials [group][seq][tile]
  __shared__ __align__(16) float outstage[32 * 52];   // [seq][t], stride 52

  const int tid = threadIdx.x;
  const int w = tid >> 6;
  const int l = tid & 63;
  const int c = l & 15;        // tile column / seq-in-group
  const int grp = l >> 4;      // 0..3
  const int klo = 8 * grp;     // within-K-tile offset
  const int seqbase = blockIdx.x * 32;
  const int u = 16 * w + c;    // this lane's hidden unit
  const bool vu = (u < 100);
  const float padf = (u == 100) ? 1.f : 0.f;  // constant-1 bias column at unit 100

  // init LDS h-buffers: pad cols zero except col 100 = 1.0
  for (int i = tid; i < 2 * 32 * 136; i += 448)
    hbuf[0][i] = (__bf16)((i % 136 == 100) ? 1.f : 0.f);

  // per-lane constants (pre-scaled)
  float wihr = 0.f, wihz = 0.f, wihn = 0.f, bin_ = 0.f;
  if (vu) {
    wihr = w_ih[u] * LOG2E;
    wihz = w_ih[100 + u] * LOG2E;
    wihn = w_ih[200 + u] * (2.f * LOG2E);
    bin_ = b_ih[200 + u] * (2.f * LOG2E);
  }
  // y-task assignment + resident wY frags (transposed: w1 rows as MFMA A operand)
  const int ytile = (w < 3) ? w : ((w == 3) ? 3 : (w - 4));
  const int yg0 = (w < 4) ? 0 : 1;   // group for single-task waves
  const bool dual = (w == 3);
  bf16x8 wY[4];
  #pragma unroll
  for (int kt = 0; kt < 4; ++kt)
    wY[kt] = *(const bf16x8*)(ws + WS_W1 + (ytile * 16 + c) * 128 + kt * 32 + klo);
  float w2v[4];
  #pragma unroll
  for (int r = 0; r < 4; ++r) {
    int yu = ytile * 16 + 4 * grp + r;
    w2v[r] = (yu < 50) ? w2[yu] : 0.f;
  }
  const float b2v = b2[0];

  // resident w_hh fragments (shared across both seq groups)
  bf16x8 wR[3][4];
  #pragma unroll
  for (int g = 0; g < 3; ++g) {
    #pragma unroll
    for (int kt = 0; kt < 4; ++kt)
      wR[g][kt] = *(const bf16x8*)(ws + WS_WHH + (g * 112 + u) * 128 + kt * 32 + klo);
  }

  // ---------- encoder: h0 = tanh(sig @ Weff^T), DFT + bias folded into Weff ----------
  float h_old[2][4];
  {
    #pragma unroll
    for (int g = 0; g < 2; ++g) {
      f32x4 hc = {0.f, 0.f, 0.f, 0.f};
      const float* srow = enc + (size_t)(seqbase + 16 * g + c) * 100;
      #pragma unroll
      for (int kt = 0; kt < 4; ++kt) {
        bf16x8 wE = *(const bf16x8*)(ws + WS_WENC + u * 128 + kt * 32 + klo);
        int t0 = kt * 32 + klo;
        float f0 = 0.f, f1 = 0.f, f2 = 0.f, f3 = 0.f, f4 = 0.f, f5 = 0.f, f6 = 0.f, f7 = 0.f;
        if (t0 + 8 <= 100) {
          float4 va = *(const float4*)(srow + t0);
          float4 vb = *(const float4*)(srow + t0 + 4);
          f0 = va.x; f1 = va.y; f2 = va.z; f3 = va.w;
          f4 = vb.x; f5 = vb.y; f6 = vb.z; f7 = vb.w;
        } else if (t0 < 100) {  // t0 == 96: 4 real + slot 100 = 1.0 (bias)
          float4 va = *(const float4*)(srow + t0);
          f0 = va.x; f1 = va.y; f2 = va.z; f3 = va.w;
          f4 = 1.f;
        }
        bf16x8 a;
        a[0] = (__bf16)f0; a[1] = (__bf16)f1; a[2] = (__bf16)f2; a[3] = (__bf16)f3;
        a[4] = (__bf16)f4; a[5] = (__bf16)f5; a[6] = (__bf16)f6; a[7] = (__bf16)f7;
        hc = mfma16(a, wE, hc);
      }
      #pragma unroll
      for (int r = 0; r < 4; ++r) h_old[g][r] = vu ? tanh2(hc[r]) : 0.f;
    }
  }
  // x at t=0 is the last encoder input sample
  float x0[2][4];
  #pragma unroll
  for (int g = 0; g < 2; ++g)
    #pragma unroll
    for (int r = 0; r < 4; ++r)
      x0[g][r] = enc[(size_t)(seqbase + 16 * g + 4 * grp + r) * 100 + 99];

  __syncthreads();  // LDS init complete
  #pragma unroll
  for (int g = 0; g < 2; ++g)
    #pragma unroll
    for (int r = 0; r < 4; ++r)
      hbuf[0][(16 * g + 4 * grp + r) * 136 + u] = (__bf16)(vu ? h_old[g][r] : padf);
  __syncthreads();

  // ---------- decoder: t=0..50; interval t computes y_{t-1} (t>0) and h_{t+1} (t<50) ----------
  #pragma unroll 1
  for (int t = 0; t <= 50; ++t) {
    const int rb = t & 1;
    // ---- y-phase (transposed): Cy rows = y-units, cols = seqs ----
    if (t > 0) {
      const int ntask = dual ? 2 : 1;
      #pragma unroll 1
      for (int gi = 0; gi < ntask; ++gi) {
        const int g = dual ? gi : yg0;
        f32x4 Cy = {0.f, 0.f, 0.f, 0.f};
        #pragma unroll
        for (int kt = 0; kt < 4; ++kt) {
          bf16x8 ag = *(const bf16x8*)&hbuf[rb][(16 * g + c) * 136 + kt * 32 + klo];
          Cy = mfma16(wY[kt], ag, Cy);
        }
        float p = 0.f;
        #pragma unroll
        for (int r = 0; r < 4; ++r) {
          float v = Cy[r];
          v = fmaxf(v, 0.01f * v);     // leaky_relu (b1 folded via bias column)
          p = fmaf(w2v[r], v, p);
        }
        p += __shfl_xor(p, 16);
        p += __shfl_xor(p, 32);
        if (l < 16) xq[g][l][ytile] = p;
      }
    }
    // ---- gate MFMAs for both groups (a-frags loaded per use; acc lives across B1) ----
    f32x4 Cr[2], Cz[2], Cn[2];
    if (t < 50) {
      #pragma unroll
      for (int g = 0; g < 2; ++g) {
        Cr[g] = f32x4{0.f, 0.f, 0.f, 0.f};
        Cz[g] = f32x4{0.f, 0.f, 0.f, 0.f};
        Cn[g] = f32x4{0.f, 0.f, 0.f, 0.f};
        #pragma unroll
        for (int kt = 0; kt < 4; ++kt) {
          bf16x8 a = *(const bf16x8*)&hbuf[rb][(16 * g + c) * 136 + kt * 32 + klo];
          Cr[g] = mfma16(a, wR[0][kt], Cr[g]);
          Cz[g] = mfma16(a, wR[1][kt], Cz[g]);
          Cn[g] = mfma16(a, wR[2][kt], Cn[g]);
        }
      }
    }
    __syncthreads();  // barrier 1: xq ready

    // ---- xv assembly + out staging + elementwise ----
    float xv[2][4];
    if (t > 0) {
      #pragma unroll
      for (int g = 0; g < 2; ++g) {
        #pragma unroll
        for (int r = 0; r < 4; ++r) {
          float4 xp = *(const float4*)xq[g][4 * grp + r];
          xv[g][r] = b2v + xp.x + xp.y + xp.z + xp.w;
        }
        if (c == 0 && w == 3 * g) {   // wave 0 stages g0, wave 3 stages g1 (LDS only)
          #pragma unroll
          for (int r = 0; r < 4; ++r)
            outstage[(16 * g + 4 * grp + r) * 52 + (t - 1)] = xv[g][r];
        }
      }
    } else {
      #pragma unroll
      for (int g = 0; g < 2; ++g)
        #pragma unroll
        for (int r = 0; r < 4; ++r)
          xv[g][r] = x0[g][r];
    }
    if (t < 50) {
      const int wb = rb ^ 1;
      #pragma unroll
      for (int g = 0; g < 2; ++g) {
        #pragma unroll
        for (int r = 0; r < 4; ++r) {
          float ar = fmaf(xv[g][r], wihr, Cr[g][r]);   // log2e-scaled, bias included
          float rg = sigm2(ar);
          float az = fmaf(xv[g][r], wihz, Cz[g][r]);
          float zg = sigm2(az);
          float bn = fmaf(rg, Cn[g][r], fmaf(xv[g][r], wihn, bin_));  // 2log2e-scaled
          float ng = tanh2(bn);
          float hn = fmaf(zg, h_old[g][r] - ng, ng);
          h_old[g][r] = hn;
          hbuf[wb][(16 * g + 4 * grp + r) * 136 + u] = (__bf16)(vu ? hn : padf);
        }
      }
    }
    __syncthreads();  // barrier 2: h ready for next step
  }

  // ---------- coalesced output flush ----------
  for (int i = tid; i < 32 * 50; i += 448) {
    int s = i / 50, tp = i - s * 50;
    out[(size_t)(seqbase + s) * 50 + tp] = outstage[s * 52 + tp];
  }
}

extern "C" void kernel_launch(void* const* d_in, const int* in_sizes, int n_in,
                              void* d_out, int out_size, void* d_ws, size_t ws_size,
                              hipStream_t stream) {
  const float* enc   = (const float*)d_in[0];
  const float* w_enc = (const float*)d_in[1];
  const float* b_enc = (const float*)d_in[2];
  const float* w_ih  = (const float*)d_in[3];
  const float* b_ih  = (const float*)d_in[4];
  const float* w_hh  = (const float*)d_in[5];
  const float* b_hh  = (const float*)d_in[6];
  const float* w1    = (const float*)d_in[7];
  const float* b1    = (const float*)d_in[8];
  const float* w2    = (const float*)d_in[9];
  const float* b2    = (const float*)d_in[10];
  __bf16* ws = (__bf16*)d_ws;
  float* out = (float*)d_out;

  prep_kernel<<<256, 256, 0, stream>>>(w_enc, b_enc, w_hh, b_ih, b_hh, w1, b1, ws);
  gru_main<<<32768 / 32, 448, 0, stream>>>(enc, w_ih, b_ih, w2, b2, ws, out);
}

// Round 8
// 318.834 us; speedup vs baseline: 1.3510x; 1.3510x over previous
//
#include <hip/hip_runtime.h>

typedef __bf16 bf16x8 __attribute__((ext_vector_type(8)));
typedef float f32x4 __attribute__((ext_vector_type(4)));

// workspace layout (bf16 elements):
//   [0)      Weff   [112][128]  (unit, k)  pre-scaled by 2*log2e, col100 = 2*log2e*b_enc
//   [14336)  whh_p  [3][112][128]          r,z pre-scaled by log2e (col100 = log2e*(b_ih+b_hh));
//                                          n pre-scaled by 2*log2e (col100 = 2*log2e*b_hh_n)
//   [57344)  w1_p   [64][128]  (yunit, k)  col100 = b1
#define WS_WENC 0
#define WS_WHH  14336
#define WS_W1   57344
#define LOG2E 1.4426950408889634f

__device__ __forceinline__ float fast_exp2(float x) {
#if __has_builtin(__builtin_amdgcn_exp2f)
  return __builtin_amdgcn_exp2f(x);
#else
  return exp2f(x);
#endif
}
__device__ __forceinline__ float fast_rcp(float x) {
#if __has_builtin(__builtin_amdgcn_rcpf)
  return __builtin_amdgcn_rcpf(x);
#else
  return 1.f / x;
#endif
}

__global__ void prep_kernel(const float* __restrict__ w_enc,
                            const float* __restrict__ b_enc,
                            const float* __restrict__ w_hh,
                            const float* __restrict__ b_ih,
                            const float* __restrict__ b_hh,
                            const float* __restrict__ w1,
                            const float* __restrict__ b1,
                            __bf16* __restrict__ ws) {
  int idx = blockIdx.x * 256 + threadIdx.x;
  if (idx < 14336) {
    // Weff[i][n] = w_enc[i][n] + sum_k w_enc[i][100+k]*cos(2pi k n/100) - w_enc[i][151+k]*sin(2pi k n/100)
    int i = idx >> 7, n = idx & 127;
    float acc = 0.f;
    if (i < 100) {
      if (n < 100) {
        const float* wr = w_enc + i * 202;
        acc = wr[n];
        #pragma unroll 1
        for (int k = 0; k <= 50; ++k) {
          int m = (k * n) % 100;                 // exact range reduction
          float th = 0.062831853071795864f * (float)m;
          float s, c;
          __sincosf(th, &s, &c);
          acc += wr[100 + k] * c - wr[151 + k] * s;
        }
        acc *= 2.f * LOG2E;
      } else if (n == 100) {
        acc = 2.f * LOG2E * b_enc[i];
      }
    }
    ws[idx] = (__bf16)acc;
  } else if (idx < 57344) {
    int j = idx - 14336;
    int g = j / 14336;
    int rem = j - g * 14336;
    int u2 = rem >> 7, c2 = rem & 127;
    float scale = (g == 2) ? 2.f * LOG2E : LOG2E;
    float v = 0.f;
    if (u2 < 100) {
      if (c2 < 100) v = scale * w_hh[(g * 100 + u2) * 100 + c2];
      else if (c2 == 100) {
        v = (g == 2) ? scale * b_hh[200 + u2]
                     : scale * (b_ih[g * 100 + u2] + b_hh[g * 100 + u2]);
      }
    }
    ws[idx] = (__bf16)v;
  } else if (idx < 65536) {
    int j = idx - 57344;
    int r2 = j >> 7, c2 = j & 127;
    float v = 0.f;
    if (r2 < 50) {
      if (c2 < 100) v = w1[r2 * 100 + c2];
      else if (c2 == 100) v = b1[r2];
    }
    ws[idx] = (__bf16)v;
  }
}

__device__ __forceinline__ f32x4 mfma16(bf16x8 a, bf16x8 b, f32x4 c) {
  return __builtin_amdgcn_mfma_f32_16x16x32_bf16(a, b, c, 0, 0, 0);
}
// input already scaled by log2e:  sigm = rcp(1 + 2^-a)
__device__ __forceinline__ float sigm2(float a) { return fast_rcp(1.f + fast_exp2(-a)); }
// input already scaled by 2*log2e: tanh = 2*rcp(1 + 2^-b) - 1
__device__ __forceinline__ float tanh2(float b) { return fmaf(2.f, fast_rcp(1.f + fast_exp2(-b)), -1.f); }

// block = 448 threads = 7 waves, 32 sequences per block (two 16-seq MFMA groups
// sharing the per-wave resident w_hh fragments).
// wave w owns hidden units [16w, 16w+16) for BOTH groups.
// y-matmul transposed (w1 tile as A from LDS wYl, h as B): reduction = 4 in-lane fma
// + 2 shfl_xor. y-tasks: waves 0-2 -> g0 tiles 0-2; wave 3 -> tile 3 both groups;
// waves 4-6 -> g1 tiles 0-2.
// REGISTER DIET (R7/R8 lesson): occupancy is capped by combined VGPR+AGPR (~12 waves
// at ~160 regs, the unified gfx950 file), NOT by LDS. So: wY in LDS (R7's residency
// spilled); g1 gate MFMAs issued AFTER barrier 1 (halves cross-barrier accumulators,
// latency hides under g0's xv+elementwise); x0 read from enc at t==0 directly;
// w2 via LDS broadcast. Target <=136 regs/wave -> 14-16 waves/CU.
// Output staged in LDS, flushed coalesced after the loop: no in-loop global stores.
// MFMA 16x16x32_bf16; C/D layout: col = lane&15, row = 4*(lane>>4)+reg (HW-verified).
// Bias trick: h column 100 pinned to 1.0; weight column 100 carries the biases.
// All LDS tiles stride 136 elements (272 B) -> 2-way bank aliasing only (free).
__global__ __launch_bounds__(448, 4)
void gru_main(const float* __restrict__ enc,
              const float* __restrict__ w_ih,
              const float* __restrict__ b_ih,
              const float* __restrict__ w2,
              const float* __restrict__ b2,
              const __bf16* __restrict__ ws,
              float* __restrict__ out) {
  __shared__ __align__(16) __bf16 hbuf[2][32 * 136];  // [buf][seq 0..31][unit]
  __shared__ __align__(16) __bf16 wYl[64 * 136];      // w1_p restrided 128->136
  __shared__ __align__(16) float xq[2][16][4];        // y tile-partials [group][seq][tile]
  __shared__ __align__(16) float outstage[32 * 52];   // [seq][t], stride 52
  __shared__ float w2l[64];

  const int tid = threadIdx.x;
  const int w = tid >> 6;
  const int l = tid & 63;
  const int c = l & 15;        // tile column / seq-in-group
  const int grp = l >> 4;      // 0..3
  const int klo = 8 * grp;     // within-K-tile offset
  const int seqbase = blockIdx.x * 32;
  const int u = 16 * w + c;    // this lane's hidden unit
  const bool vu = (u < 100);
  const float padf = (u == 100) ? 1.f : 0.f;  // constant-1 bias column at unit 100

  // init LDS h-buffers: pad cols zero except col 100 = 1.0
  for (int i = tid; i < 2 * 32 * 136; i += 448)
    hbuf[0][i] = (__bf16)((i % 136 == 100) ? 1.f : 0.f);
  // stage w1_p into LDS with stride restrip 128 -> 136 (1024 16B chunks)
  for (int i = tid; i < 1024; i += 448) {
    int row = i >> 4, off = (i & 15) * 8;
    *(bf16x8*)&wYl[row * 136 + off] = *(const bf16x8*)(ws + WS_W1 + row * 128 + off);
  }
  if (tid < 64) w2l[tid] = (tid < 50) ? w2[tid] : 0.f;

  // per-lane constants (pre-scaled)
  float wihr = 0.f, wihz = 0.f, wihn = 0.f, bin_ = 0.f;
  if (vu) {
    wihr = w_ih[u] * LOG2E;
    wihz = w_ih[100 + u] * LOG2E;
    wihn = w_ih[200 + u] * (2.f * LOG2E);
    bin_ = b_ih[200 + u] * (2.f * LOG2E);
  }
  // y-task assignment
  const int ytile = (w < 3) ? w : ((w == 3) ? 3 : (w - 4));
  const int yg0 = (w < 4) ? 0 : 1;
  const bool dual = (w == 3);
  const float b2v = b2[0];

  // resident w_hh fragments (shared across both seq groups)
  bf16x8 wR[3][4];
  #pragma unroll
  for (int g = 0; g < 3; ++g) {
    #pragma unroll
    for (int kt = 0; kt < 4; ++kt)
      wR[g][kt] = *(const bf16x8*)(ws + WS_WHH + (g * 112 + u) * 128 + kt * 32 + klo);
  }

  // ---------- encoder: h0 = tanh(sig @ Weff^T), DFT + bias folded into Weff ----------
  float h_old[2][4];
  {
    #pragma unroll
    for (int g = 0; g < 2; ++g) {
      f32x4 hc = {0.f, 0.f, 0.f, 0.f};
      const float* srow = enc + (size_t)(seqbase + 16 * g + c) * 100;
      #pragma unroll
      for (int kt = 0; kt < 4; ++kt) {
        bf16x8 wE = *(const bf16x8*)(ws + WS_WENC + u * 128 + kt * 32 + klo);
        int t0 = kt * 32 + klo;
        float f0 = 0.f, f1 = 0.f, f2 = 0.f, f3 = 0.f, f4 = 0.f, f5 = 0.f, f6 = 0.f, f7 = 0.f;
        if (t0 + 8 <= 100) {
          float4 va = *(const float4*)(srow + t0);
          float4 vb = *(const float4*)(srow + t0 + 4);
          f0 = va.x; f1 = va.y; f2 = va.z; f3 = va.w;
          f4 = vb.x; f5 = vb.y; f6 = vb.z; f7 = vb.w;
        } else if (t0 < 100) {  // t0 == 96: 4 real + slot 100 = 1.0 (bias)
          float4 va = *(const float4*)(srow + t0);
          f0 = va.x; f1 = va.y; f2 = va.z; f3 = va.w;
          f4 = 1.f;
        }
        bf16x8 a;
        a[0] = (__bf16)f0; a[1] = (__bf16)f1; a[2] = (__bf16)f2; a[3] = (__bf16)f3;
        a[4] = (__bf16)f4; a[5] = (__bf16)f5; a[6] = (__bf16)f6; a[7] = (__bf16)f7;
        hc = mfma16(a, wE, hc);
      }
      #pragma unroll
      for (int r = 0; r < 4; ++r) h_old[g][r] = vu ? tanh2(hc[r]) : 0.f;
    }
  }

  __syncthreads();  // LDS init + wYl/w2l staging complete
  #pragma unroll
  for (int g = 0; g < 2; ++g)
    #pragma unroll
    for (int r = 0; r < 4; ++r)
      hbuf[0][(16 * g + 4 * grp + r) * 136 + u] = (__bf16)(vu ? h_old[g][r] : padf);
  __syncthreads();

  // ---------- decoder: t=0..50; interval t computes y_{t-1} (t>0) and h_{t+1} (t<50) ----------
  #pragma unroll 1
  for (int t = 0; t <= 50; ++t) {
    const int rb = t & 1;
    // ---- y-phase (transposed): Cy rows = y-units, cols = seqs ----
    if (t > 0) {
      const int ntask = dual ? 2 : 1;
      #pragma unroll 1
      for (int gi = 0; gi < ntask; ++gi) {
        const int g = dual ? gi : yg0;
        f32x4 Cy = {0.f, 0.f, 0.f, 0.f};
        #pragma unroll
        for (int kt = 0; kt < 4; ++kt) {
          bf16x8 wyf = *(const bf16x8*)&wYl[(ytile * 16 + c) * 136 + kt * 32 + klo];
          bf16x8 ag = *(const bf16x8*)&hbuf[rb][(16 * g + c) * 136 + kt * 32 + klo];
          Cy = mfma16(wyf, ag, Cy);
        }
        float p = 0.f;
        #pragma unroll
        for (int r = 0; r < 4; ++r) {
          float v = Cy[r];
          v = fmaxf(v, 0.01f * v);     // leaky_relu (b1 folded via bias column)
          p = fmaf(w2l[ytile * 16 + 4 * grp + r], v, p);
        }
        p += __shfl_xor(p, 16);
        p += __shfl_xor(p, 32);
        if (l < 16) xq[g][l][ytile] = p;
      }
    }
    // ---- gate MFMAs for GROUP 0 only before B1 (halve cross-barrier accs) ----
    f32x4 Cr0 = {0.f,0.f,0.f,0.f}, Cz0 = {0.f,0.f,0.f,0.f}, Cn0 = {0.f,0.f,0.f,0.f};
    if (t < 50) {
      #pragma unroll
      for (int kt = 0; kt < 4; ++kt) {
        bf16x8 a = *(const bf16x8*)&hbuf[rb][c * 136 + kt * 32 + klo];
        Cr0 = mfma16(a, wR[0][kt], Cr0);
        Cz0 = mfma16(a, wR[1][kt], Cz0);
        Cn0 = mfma16(a, wR[2][kt], Cn0);
      }
    }
    __syncthreads();  // barrier 1: xq ready

    if (t < 50) {
      const int wb = rb ^ 1;
      // ---- group 1 gate MFMAs issued FIRST (hbuf[rb] still valid; latency hides
      //      under g0's xv assembly + elementwise) ----
      f32x4 Cr1 = {0.f,0.f,0.f,0.f}, Cz1 = {0.f,0.f,0.f,0.f}, Cn1 = {0.f,0.f,0.f,0.f};
      #pragma unroll
      for (int kt = 0; kt < 4; ++kt) {
        bf16x8 a = *(const bf16x8*)&hbuf[rb][(16 + c) * 136 + kt * 32 + klo];
        Cr1 = mfma16(a, wR[0][kt], Cr1);
        Cz1 = mfma16(a, wR[1][kt], Cz1);
        Cn1 = mfma16(a, wR[2][kt], Cn1);
      }
      // ---- group 0: xv + out staging + elementwise + h write ----
      {
        float xv[4];
        if (t > 0) {
          #pragma unroll
          for (int r = 0; r < 4; ++r) {
            float4 xp = *(const float4*)xq[0][4 * grp + r];
            xv[r] = b2v + xp.x + xp.y + xp.z + xp.w;
          }
          if (c == 0 && w == 0) {
            #pragma unroll
            for (int r = 0; r < 4; ++r)
              outstage[(4 * grp + r) * 52 + (t - 1)] = xv[r];
          }
        } else {
          #pragma unroll
          for (int r = 0; r < 4; ++r)
            xv[r] = enc[(size_t)(seqbase + 4 * grp + r) * 100 + 99];
        }
        #pragma unroll
        for (int r = 0; r < 4; ++r) {
          float ar = fmaf(xv[r], wihr, Cr0[r]);
          float rg = sigm2(ar);
          float az = fmaf(xv[r], wihz, Cz0[r]);
          float zg = sigm2(az);
          float bn = fmaf(rg, Cn0[r], fmaf(xv[r], wihn, bin_));
          float ng = tanh2(bn);
          float hn = fmaf(zg, h_old[0][r] - ng, ng);
          h_old[0][r] = hn;
          hbuf[wb][(4 * grp + r) * 136 + u] = (__bf16)(vu ? hn : padf);
        }
      }
      // ---- group 1: xv + out staging + elementwise + h write ----
      {
        float xv[4];
        if (t > 0) {
          #pragma unroll
          for (int r = 0; r < 4; ++r) {
            float4 xp = *(const float4*)xq[1][4 * grp + r];
            xv[r] = b2v + xp.x + xp.y + xp.z + xp.w;
          }
          if (c == 0 && w == 3) {
            #pragma unroll
            for (int r = 0; r < 4; ++r)
              outstage[(16 + 4 * grp + r) * 52 + (t - 1)] = xv[r];
          }
        } else {
          #pragma unroll
          for (int r = 0; r < 4; ++r)
            xv[r] = enc[(size_t)(seqbase + 16 + 4 * grp + r) * 100 + 99];
        }
        #pragma unroll
        for (int r = 0; r < 4; ++r) {
          float ar = fmaf(xv[r], wihr, Cr1[r]);
          float rg = sigm2(ar);
          float az = fmaf(xv[r], wihz, Cz1[r]);
          float zg = sigm2(az);
          float bn = fmaf(rg, Cn1[r], fmaf(xv[r], wihn, bin_));
          float ng = tanh2(bn);
          float hn = fmaf(zg, h_old[1][r] - ng, ng);
          h_old[1][r] = hn;
          hbuf[wb][(16 + 4 * grp + r) * 136 + u] = (__bf16)(vu ? hn : padf);
        }
      }
    } else {
      // t == 50: only the final out staging (y_49)
      #pragma unroll
      for (int g = 0; g < 2; ++g) {
        if (c == 0 && w == 3 * g) {
          #pragma unroll
          for (int r = 0; r < 4; ++r) {
            float4 xp = *(const float4*)xq[g][4 * grp + r];
            outstage[(16 * g + 4 * grp + r) * 52 + (t - 1)] =
                b2v + xp.x + xp.y + xp.z + xp.w;
          }
        }
      }
    }
    __syncthreads();  // barrier 2: h ready for next step
  }

  // ---------- coalesced output flush ----------
  for (int i = tid; i < 32 * 50; i += 448) {
    int s = i / 50, tp = i - s * 50;
    out[(size_t)(seqbase + s) * 50 + tp] = outstage[s * 52 + tp];
  }
}

extern "C" void kernel_launch(void* const* d_in, const int* in_sizes, int n_in,
                              void* d_out, int out_size, void* d_ws, size_t ws_size,
                              hipStream_t stream) {
  const float* enc   = (const float*)d_in[0];
  const float* w_enc = (const float*)d_in[1];
  const float* b_enc = (const float*)d_in[2];
  const float* w_ih  = (const float*)d_in[3];
  const float* b_ih  = (const float*)d_in[4];
  const float* w_hh  = (const float*)d_in[5];
  const float* b_hh  = (const float*)d_in[6];
  const float* w1    = (const float*)d_in[7];
  const float* b1    = (const float*)d_in[8];
  const float* w2    = (const float*)d_in[9];
  const float* b2    = (const float*)d_in[10];
  __bf16* ws = (__bf16*)d_ws;
  float* out = (float*)d_out;

  prep_kernel<<<256, 256, 0, stream>>>(w_enc, b_enc, w_hh, b_ih, b_hh, w1, b1, ws);
  gru_main<<<32768 / 32, 448, 0, stream>>>(enc, w_ih, b_ih, w2, b2, ws, out);
}